// Round 6
// baseline (564.716 us; speedup 1.0000x reference)
//
#include <hip/hip_runtime.h>
#include <hip/hip_bf16.h>

#define D_MODEL 1024
#define HEAD    64
#define SEQ     2048
#define BATCH   4
#define ROWS    (BATCH * SEQ)   // 8192

typedef __attribute__((ext_vector_type(8))) short  short8;   // 8 bf16
typedef __attribute__((ext_vector_type(4))) short  short4v;  // 4 bf16
typedef __attribute__((ext_vector_type(4))) float  f32x4;

__device__ __forceinline__ unsigned short f2bf(float f) {
    union { __hip_bfloat16 h; unsigned short u; } c;
    c.h = __float2bfloat16(f);
    return c.u;
}

// ---------------------------------------------------------------------------
// Kernel 0: W[1024][64] f32 -> Wt[192][1024] bf16 (transposed, q|k|v concat).
// ---------------------------------------------------------------------------
__global__ __launch_bounds__(256) void conv_w(
    const float* __restrict__ Wq, const float* __restrict__ Wk,
    const float* __restrict__ Wv, unsigned short* __restrict__ Wt)
{
    __shared__ float Lw[64][65];
    const int tid = threadIdx.x;
    const int mat = blockIdx.x >> 4;
    const int k0  = (blockIdx.x & 15) * 64;
    const float* W = (mat == 0) ? Wq : (mat == 1 ? Wk : Wv);

    #pragma unroll
    for (int j = 0; j < 4; ++j) {
        const int idx = j * 1024 + tid * 4;
        const int r = idx >> 6, c = idx & 63;
        f32x4 v4 = *(const f32x4*)(W + (size_t)(k0 + r) * HEAD + c);
        Lw[r][c] = v4[0]; Lw[r][c+1] = v4[1]; Lw[r][c+2] = v4[2]; Lw[r][c+3] = v4[3];
    }
    __syncthreads();

    const int col = tid >> 2, kc = (tid & 3) * 16;
    short8 o0, o1;
    #pragma unroll
    for (int j = 0; j < 8; ++j) o0[j] = f2bf(Lw[kc + j][col]);
    #pragma unroll
    for (int j = 0; j < 8; ++j) o1[j] = f2bf(Lw[kc + 8 + j][col]);
    unsigned short* dst = Wt + (size_t)(mat * 64 + col) * D_MODEL + k0 + kc;
    *(short8*)(dst)     = o0;
    *(short8*)(dst + 8) = o1;
}

// ---------------------------------------------------------------------------
// Kernel 1: MFMA bf16 GEMM  C[8192][192] = x . Wt^T + b.
// BM=16, grid 512, 4 waves (wave w = 48-col slice). x row-panel staged to LDS
// ONCE (bf16, pad-1032), then 16 barrier-free iters: A-frags from LDS,
// B-frags straight from L2-resident Wt (coalesced 64B/row segments).
// Outputs: qb bf16 (x0.125), kb bf16, V^T bf16 via small LDS roundtrip.
// ---------------------------------------------------------------------------
__global__ __launch_bounds__(256) void gemm_qkv(
    const float* __restrict__ x, const unsigned short* __restrict__ Wt,
    const float* __restrict__ bq, const float* __restrict__ bk,
    const float* __restrict__ bv,
    unsigned short* __restrict__ qb, unsigned short* __restrict__ kb,
    unsigned short* __restrict__ vt)
{
    __shared__ unsigned short Xs[16 * 1032];     // 33 KB, pad 1032: 2-way reads
    __shared__ float Vx[16][66];                 // 4.2 KB

    const int tid  = threadIdx.x;
    const int lane = tid & 63;
    const int w    = tid >> 6;        // 0..3: col slice w*48
    const int l15  = lane & 15;
    const int g    = lane >> 4;
    const int row0 = blockIdx.x * 16;

    // ---- stage x panel (16 rows x 1024) as bf16 ----
    {
        const int xrow = tid >> 4;
        const int cbase = (tid & 15) * 4;
        #pragma unroll
        for (int j = 0; j < 16; ++j) {
            const int col = j * 64 + cbase;
            f32x4 v4 = *(const f32x4*)(x + (size_t)(row0 + xrow) * D_MODEL + col);
            short4v pk;
            pk[0] = f2bf(v4[0]); pk[1] = f2bf(v4[1]);
            pk[2] = f2bf(v4[2]); pk[3] = f2bf(v4[3]);
            *(short4v*)&Xs[xrow * 1032 + col] = pk;
        }
    }
    __syncthreads();

    f32x4 acc[3] = {};

    #pragma unroll 4
    for (int t = 0; t < 16; ++t) {
        const int k0 = t * 64;
        short8 af0 = *(const short8*)&Xs[l15 * 1032 + k0 + g * 8];
        short8 af1 = *(const short8*)&Xs[l15 * 1032 + k0 + 32 + g * 8];
        #pragma unroll
        for (int ni = 0; ni < 3; ++ni) {
            const size_t nrow = (size_t)(w * 48 + ni * 16 + l15) * D_MODEL + k0;
            short8 b0 = *(const short8*)(Wt + nrow + g * 8);
            short8 b1 = *(const short8*)(Wt + nrow + 32 + g * 8);
            acc[ni] = __builtin_amdgcn_mfma_f32_16x16x32_bf16(af0, b0, acc[ni], 0, 0, 0);
            acc[ni] = __builtin_amdgcn_mfma_f32_16x16x32_bf16(af1, b1, acc[ni], 0, 0, 0);
        }
    }

    // ---- epilogue ----
    #pragma unroll
    for (int ni = 0; ni < 3; ++ni) {
        const int col = w * 48 + ni * 16 + l15;
        const int mat = col >> 6, mc = col & 63;
        const float bias = (mat == 0 ? bq : (mat == 1 ? bk : bv))[mc];
        #pragma unroll
        for (int r = 0; r < 4; ++r) {
            const int rl = g * 4 + r;
            const float val = acc[ni][r] + bias;
            if (mat == 0)      qb[(size_t)(row0 + rl) * HEAD + mc] = f2bf(val * 0.125f);
            else if (mat == 1) kb[(size_t)(row0 + rl) * HEAD + mc] = f2bf(val);
            else               Vx[rl][mc] = val;
        }
    }
    __syncthreads();

    // transposed V store: vt[b][d][kv]
    {
        const int d = tid >> 2, kvc = (tid & 3) * 4;
        short4v o;
        #pragma unroll
        for (int j = 0; j < 4; ++j) o[j] = f2bf(Vx[kvc + j][d]);
        const int bb = row0 >> 11, kvloc = row0 & 2047;
        *(short4v*)(vt + ((size_t)bb * HEAD + d) * SEQ + kvloc + kvc) = o;
    }
}

// ---------------------------------------------------------------------------
// Kernel 2: causal flash attention, bf16 MFMA, LDS-free K/V.
// Grid (64,4) x 256 thr. Block p -> q-tiles {p, 127-p} (QB=16, balanced).
// Per 128-kv iteration each wave owns a 32-kv slice with independent
// (m,l,acc); K/V fragments loaded DIRECTLY from L2-resident global memory
// (coalesced 64B row segments); K reg-double-buffered. ZERO barriers in the
// kv loop; flash-decoding merge once per q-tile.
// ---------------------------------------------------------------------------
__global__ __launch_bounds__(256, 4) void attn_fwd(
    const unsigned short* __restrict__ qb, const unsigned short* __restrict__ kb,
    const unsigned short* __restrict__ vt, float* __restrict__ out)
{
    __shared__ unsigned short Qs[16 * 68];       // 2.2 KB
    __shared__ unsigned short Ps[4][16 * 40];    // 5 KB (wave-private P)
    __shared__ float Cs[4][16 * 68];             // 17.4 KB (merge)
    __shared__ float Sm[64], Sl[64];

    const int tid  = threadIdx.x;
    const int lane = tid & 63;
    const int w    = tid >> 6;
    const int l15  = lane & 15;
    const int g    = lane >> 4;
    const int b    = blockIdx.y;
    const int p    = blockIdx.x;

    const unsigned short* qg = qb + (size_t)b * SEQ * HEAD;
    const unsigned short* kg = kb + (size_t)b * SEQ * HEAD;
    const unsigned short* vg = vt + (size_t)b * HEAD * SEQ;

    #pragma unroll 1
    for (int half = 0; half < 2; ++half) {
        const int j     = half ? (127 - p) : p;
        const int q0    = j * 16;
        const int iters = ((q0 + 16) + 127) >> 7;

        // ---- stage Q tile ----
        if (tid < 128) {
            const int row = tid >> 3, slot = tid & 7;
            *(short8*)&Qs[row * 68 + slot * 8] =
                *(const short8*)(qg + (size_t)(q0 + row) * HEAD + slot * 8);
        }
        __syncthreads();

        short8 qf0 = *(const short8*)&Qs[l15 * 68 + g * 8];
        short8 qf1 = *(const short8*)&Qs[l15 * 68 + 32 + g * 8];

        float m_w = -1.0e30f, l_w = 0.0f;
        f32x4 acc[4] = {};

        // ---- prologue: K fragments for iter 0 ----
        short8 kB[2][4];
        #pragma unroll
        for (int u = 0; u < 4; ++u) {
            const int f = u >> 1, ks = u & 1;
            kB[0][u] = *(const short8*)(
                kg + (size_t)(w * 32 + f * 16 + l15) * HEAD + ks * 32 + g * 8);
        }

        #pragma unroll 2
        for (int it = 0; it < iters; ++it) {
            const int kv0 = it * 128;
            const int pb  = it & 1;

            // ---- V fragments for current iter (consumed after softmax) ----
            short8 vc[4];
            #pragma unroll
            for (int ni = 0; ni < 4; ++ni)
                vc[ni] = *(const short8*)(
                    vg + (size_t)(ni * 16 + l15) * SEQ + kv0 + w * 32 + g * 8);

            // ---- K prefetch for next iter ----
            if (it + 1 < iters) {
                #pragma unroll
                for (int u = 0; u < 4; ++u) {
                    const int f = u >> 1, ks = u & 1;
                    kB[pb ^ 1][u] = *(const short8*)(
                        kg + (size_t)(kv0 + 128 + w * 32 + f * 16 + l15) * HEAD
                           + ks * 32 + g * 8);
                }
            }

            // ---- QK^T (swapped): S^T[kv 32][q 16] ----
            f32x4 sA[2] = {};
            sA[0] = __builtin_amdgcn_mfma_f32_16x16x32_bf16(kB[pb][0], qf0, sA[0], 0, 0, 0);
            sA[0] = __builtin_amdgcn_mfma_f32_16x16x32_bf16(kB[pb][1], qf1, sA[0], 0, 0, 0);
            sA[1] = __builtin_amdgcn_mfma_f32_16x16x32_bf16(kB[pb][2], qf0, sA[1], 0, 0, 0);
            sA[1] = __builtin_amdgcn_mfma_f32_16x16x32_bf16(kB[pb][3], qf1, sA[1], 0, 0, 0);

            // ---- causal mask (only last iter crosses the diagonal) ----
            if (it == iters - 1) {
                const int kvb = kv0 + w * 32 + g * 4;
                const int qg_ = q0 + l15;
                #pragma unroll
                for (int f = 0; f < 2; ++f)
                    #pragma unroll
                    for (int r = 0; r < 4; ++r)
                        if (kvb + f * 16 + r > qg_) sA[f][r] = -1.0e30f;
            }

            // ---- per-wave online softmax (q = l15, copies over g) ----
            float smax = sA[0][0];
            #pragma unroll
            for (int r = 1; r < 4; ++r) smax = fmaxf(smax, sA[0][r]);
            #pragma unroll
            for (int r = 0; r < 4; ++r) smax = fmaxf(smax, sA[1][r]);
            smax = fmaxf(smax, __shfl_xor(smax, 16));
            smax = fmaxf(smax, __shfl_xor(smax, 32));

            const float mnew = fmaxf(m_w, smax);
            const float corr = __expf(m_w - mnew);
            float pv[8], psum = 0.0f;
            #pragma unroll
            for (int f = 0; f < 2; ++f)
                #pragma unroll
                for (int r = 0; r < 4; ++r) {
                    pv[f * 4 + r] = __expf(sA[f][r] - mnew);
                    psum += pv[f * 4 + r];
                }
            psum += __shfl_xor(psum, 16);
            psum += __shfl_xor(psum, 32);
            l_w = l_w * corr + psum;
            m_w = mnew;

            // ---- pack P via wave-private LDS (no barrier needed) ----
            #pragma unroll
            for (int f = 0; f < 2; ++f) {
                short4v pk;
                pk[0] = f2bf(pv[f*4+0]); pk[1] = f2bf(pv[f*4+1]);
                pk[2] = f2bf(pv[f*4+2]); pk[3] = f2bf(pv[f*4+3]);
                *(short4v*)&Ps[w][l15 * 40 + f * 16 + g * 4] = pk;
            }

            // ---- rescale acc ----
            float cf[4];
            #pragma unroll
            for (int r = 0; r < 4; ++r) cf[r] = __shfl(corr, g * 4 + r);
            #pragma unroll
            for (int ni = 0; ni < 4; ++ni)
                #pragma unroll
                for (int r = 0; r < 4; ++r) acc[ni][r] *= cf[r];

            // ---- PV ----
            short8 pf = *(const short8*)&Ps[w][l15 * 40 + g * 8];
            #pragma unroll
            for (int ni = 0; ni < 4; ++ni)
                acc[ni] = __builtin_amdgcn_mfma_f32_16x16x32_bf16(pf, vc[ni], acc[ni], 0, 0, 0);
        }

        // ---- merge 4 wave-partials ----
        if (lane < 16) { Sm[w * 16 + lane] = m_w; Sl[w * 16 + lane] = l_w; }
        #pragma unroll
        for (int ni = 0; ni < 4; ++ni)
            #pragma unroll
            for (int r = 0; r < 4; ++r)
                Cs[w][(g * 4 + r) * 68 + ni * 16 + l15] = acc[ni][r];
        __syncthreads();

        {
            const int q = tid >> 4, d4 = (tid & 15) * 4;
            float mg = Sm[q];
            #pragma unroll
            for (int ww = 1; ww < 4; ++ww) mg = fmaxf(mg, Sm[ww * 16 + q]);
            f32x4 o = {0.f, 0.f, 0.f, 0.f};
            float lt = 0.0f;
            #pragma unroll
            for (int ww = 0; ww < 4; ++ww) {
                const float f = __expf(Sm[ww * 16 + q] - mg);
                lt += Sl[ww * 16 + q] * f;
                f32x4 c4 = *(const f32x4*)&Cs[ww][q * 68 + d4];
                o[0] += c4[0] * f; o[1] += c4[1] * f;
                o[2] += c4[2] * f; o[3] += c4[3] * f;
            }
            const float inv = 1.0f / lt;
            f32x4 res = {o[0]*inv, o[1]*inv, o[2]*inv, o[3]*inv};
            *(f32x4*)(out + ((size_t)b * SEQ + q0 + q) * HEAD + d4) = res;
        }
        __syncthreads();
    }
}

// ---------------------------------------------------------------------------
extern "C" void kernel_launch(void* const* d_in, const int* in_sizes, int n_in,
                              void* d_out, int out_size, void* d_ws, size_t ws_size,
                              hipStream_t stream) {
    const float* x  = (const float*)d_in[0];
    const float* Wq = (const float*)d_in[1];
    const float* bq = (const float*)d_in[2];
    const float* Wk = (const float*)d_in[3];
    const float* bk = (const float*)d_in[4];
    const float* Wv = (const float*)d_in[5];
    const float* bv = (const float*)d_in[6];

    unsigned short* Wt  = (unsigned short*)d_ws;                  // 384 KB
    unsigned short* qbp = Wt + (size_t)192 * D_MODEL;             // 1 MB
    unsigned short* kbp = qbp + (size_t)ROWS * HEAD;              // 1 MB
    unsigned short* vtp = kbp + (size_t)ROWS * HEAD;              // 1 MB (V^T)
    float* o = (float*)d_out;

    conv_w  <<<dim3(48),     dim3(256), 0, stream>>>(Wq, Wk, Wv, Wt);
    gemm_qkv<<<dim3(512),    dim3(256), 0, stream>>>(x, Wt, bq, bk, bv, qbp, kbp, vtp);
    attn_fwd<<<dim3(64, 4),  dim3(256), 0, stream>>>(qbp, kbp, vtp, o);
}

// Round 7
// 129.563 us; speedup vs baseline: 4.3586x; 4.3586x over previous
//
#include <hip/hip_runtime.h>
#include <hip/hip_bf16.h>

#define D_MODEL 1024
#define HEAD    64
#define SEQ     2048
#define BATCH   4
#define ROWS    (BATCH * SEQ)   // 8192

typedef __attribute__((ext_vector_type(8))) short  short8;   // 8 bf16
typedef __attribute__((ext_vector_type(4))) short  short4v;  // 4 bf16
typedef __attribute__((ext_vector_type(4))) float  f32x4;

__device__ __forceinline__ unsigned short f2bf(float f) {
    union { __hip_bfloat16 h; unsigned short u; } c;
    c.h = __float2bfloat16(f);
    return c.u;
}

// ---------------------------------------------------------------------------
// Kernel 0: W[1024][64] f32 -> Wt[192][1024] bf16 (transposed, q|k|v concat).
// ---------------------------------------------------------------------------
__global__ __launch_bounds__(256) void conv_w(
    const float* __restrict__ Wq, const float* __restrict__ Wk,
    const float* __restrict__ Wv, unsigned short* __restrict__ Wt)
{
    __shared__ float Lw[64][65];
    const int tid = threadIdx.x;
    const int mat = blockIdx.x >> 4;
    const int k0  = (blockIdx.x & 15) * 64;
    const float* W = (mat == 0) ? Wq : (mat == 1 ? Wk : Wv);

    #pragma unroll
    for (int j = 0; j < 4; ++j) {
        const int idx = j * 1024 + tid * 4;
        const int r = idx >> 6, c = idx & 63;
        f32x4 v4 = *(const f32x4*)(W + (size_t)(k0 + r) * HEAD + c);
        Lw[r][c] = v4[0]; Lw[r][c+1] = v4[1]; Lw[r][c+2] = v4[2]; Lw[r][c+3] = v4[3];
    }
    __syncthreads();

    const int col = tid >> 2, kc = (tid & 3) * 16;
    short8 o0, o1;
    #pragma unroll
    for (int j = 0; j < 8; ++j) o0[j] = f2bf(Lw[kc + j][col]);
    #pragma unroll
    for (int j = 0; j < 8; ++j) o1[j] = f2bf(Lw[kc + 8 + j][col]);
    unsigned short* dst = Wt + (size_t)(mat * 64 + col) * D_MODEL + k0 + kc;
    *(short8*)(dst)     = o0;
    *(short8*)(dst + 8) = o1;
}

// ---------------------------------------------------------------------------
// Kernel 1: MFMA bf16 GEMM  C[8192][192] = x . Wt^T + b.
// BM=16, grid 512, 4 waves (wave w = 48-col slice). x panel staged to LDS
// once; B fragments from L2-resident Wt with static double-buffered prefetch
// (paired even/odd bodies -> all reg-array indices compile-time).
// ---------------------------------------------------------------------------
__global__ __launch_bounds__(256) void gemm_qkv(
    const float* __restrict__ x, const unsigned short* __restrict__ Wt,
    const float* __restrict__ bq, const float* __restrict__ bk,
    const float* __restrict__ bv,
    unsigned short* __restrict__ qb, unsigned short* __restrict__ kb,
    unsigned short* __restrict__ vt)
{
    __shared__ unsigned short Xs[16 * 1032];     // 33 KB, pad 1032
    __shared__ float Vx[16][66];

    const int tid  = threadIdx.x;
    const int lane = tid & 63;
    const int w    = tid >> 6;
    const int l15  = lane & 15;
    const int g    = lane >> 4;
    const int row0 = blockIdx.x * 16;

    // ---- stage x panel (16 x 1024) as bf16 ----
    {
        const int xrow  = tid >> 4;
        const int cbase = (tid & 15) * 4;
        #pragma unroll
        for (int j = 0; j < 16; ++j) {
            const int col = j * 64 + cbase;
            f32x4 v4 = *(const f32x4*)(x + (size_t)(row0 + xrow) * D_MODEL + col);
            short4v pk;
            pk[0] = f2bf(v4[0]); pk[1] = f2bf(v4[1]);
            pk[2] = f2bf(v4[2]); pk[3] = f2bf(v4[3]);
            *(short4v*)&Xs[xrow * 1032 + col] = pk;
        }
    }
    __syncthreads();

    f32x4 acc[3] = {};
    const size_t wrow0 = (size_t)(w * 48 + l15) * D_MODEL;   // +ni*16*D_MODEL

    short8 bA[3][2], bB[3][2];
    // prologue: B frags for t=0
    #pragma unroll
    for (int ni = 0; ni < 3; ++ni) {
        bA[ni][0] = *(const short8*)(Wt + wrow0 + (size_t)ni * 16 * D_MODEL + g * 8);
        bA[ni][1] = *(const short8*)(Wt + wrow0 + (size_t)ni * 16 * D_MODEL + 32 + g * 8);
    }

    auto gbody = [&](int t, short8 (&bcur)[3][2], short8 (&bnxt)[3][2]) {
        const int k0 = t * 64;
        if (t + 1 < 16) {
            #pragma unroll
            for (int ni = 0; ni < 3; ++ni) {
                const size_t base = wrow0 + (size_t)ni * 16 * D_MODEL + k0 + 64;
                bnxt[ni][0] = *(const short8*)(Wt + base + g * 8);
                bnxt[ni][1] = *(const short8*)(Wt + base + 32 + g * 8);
            }
        }
        short8 af0 = *(const short8*)&Xs[l15 * 1032 + k0 + g * 8];
        short8 af1 = *(const short8*)&Xs[l15 * 1032 + k0 + 32 + g * 8];
        #pragma unroll
        for (int ni = 0; ni < 3; ++ni) {
            acc[ni] = __builtin_amdgcn_mfma_f32_16x16x32_bf16(af0, bcur[ni][0], acc[ni], 0, 0, 0);
            acc[ni] = __builtin_amdgcn_mfma_f32_16x16x32_bf16(af1, bcur[ni][1], acc[ni], 0, 0, 0);
        }
    };

    #pragma unroll 1
    for (int t = 0; t < 16; t += 2) {
        gbody(t,     bA, bB);
        gbody(t + 1, bB, bA);
    }

    // ---- epilogue ----
    #pragma unroll
    for (int ni = 0; ni < 3; ++ni) {
        const int col = w * 48 + ni * 16 + l15;
        const int mat = col >> 6, mc = col & 63;
        const float bias = (mat == 0 ? bq : (mat == 1 ? bk : bv))[mc];
        #pragma unroll
        for (int r = 0; r < 4; ++r) {
            const int rl = g * 4 + r;
            const float val = acc[ni][r] + bias;
            if (mat == 0)      qb[(size_t)(row0 + rl) * HEAD + mc] = f2bf(val * 0.125f);
            else if (mat == 1) kb[(size_t)(row0 + rl) * HEAD + mc] = f2bf(val);
            else               Vx[rl][mc] = val;
        }
    }
    __syncthreads();

    // transposed V store: vt[b][d][kv]
    {
        const int d = tid >> 2, kvc = (tid & 3) * 4;
        short4v o;
        #pragma unroll
        for (int j = 0; j < 4; ++j) o[j] = f2bf(Vx[kvc + j][d]);
        const int bb = row0 >> 11, kvloc = row0 & 2047;
        *(short4v*)(vt + ((size_t)bb * HEAD + d) * SEQ + kvloc + kvc) = o;
    }
}

// ---------------------------------------------------------------------------
// Kernel 2: causal flash attention, bf16 MFMA, LDS-free K/V, zero barriers
// in the kv loop.  Grid (64,4) x 512 thr (8 waves).  Block p -> q-tiles
// {p, 127-p} (QB=16, balanced).  Each 256-kv iteration: wave w owns the
// 32-kv slice [it*256 + w*32 ..), independent (m,l,acc).  K/V fragments
// loaded directly from L2-resident global; K statically double-buffered
// via paired even/odd bodies (no runtime reg indexing -> no scratch).
// Flash-decoding merge of the 8 wave-partials once per q-tile.
// ---------------------------------------------------------------------------
__global__ __launch_bounds__(512) void attn_fwd(
    const unsigned short* __restrict__ qb, const unsigned short* __restrict__ kb,
    const unsigned short* __restrict__ vt, float* __restrict__ out)
{
    __shared__ unsigned short Qs[16 * 68];       // 2.2 KB
    __shared__ unsigned short Ps[8][16 * 40];    // 10 KB (wave-private P)
    __shared__ float Cs[8][16 * 68];             // 34.8 KB (merge)
    __shared__ float Sm[128], Sl[128];

    const int tid  = threadIdx.x;
    const int lane = tid & 63;
    const int w    = tid >> 6;        // 0..7
    const int l15  = lane & 15;
    const int g    = lane >> 4;
    const int b    = blockIdx.y;
    const int p    = blockIdx.x;

    const unsigned short* qg = qb + (size_t)b * SEQ * HEAD;
    const unsigned short* kg = kb + (size_t)b * SEQ * HEAD;
    const unsigned short* vg = vt + (size_t)b * HEAD * SEQ;

    #pragma unroll 1
    for (int half = 0; half < 2; ++half) {
        const int j     = half ? (127 - p) : p;
        const int q0    = j * 16;
        const int iters = (q0 + 16 + 255) >> 8;     // 256 kv per iteration

        // ---- stage Q tile ----
        if (tid < 128) {
            const int row = tid >> 3, slot = tid & 7;
            *(short8*)&Qs[row * 68 + slot * 8] =
                *(const short8*)(qg + (size_t)(q0 + row) * HEAD + slot * 8);
        }
        __syncthreads();

        const short8 qf0 = *(const short8*)&Qs[l15 * 68 + g * 8];
        const short8 qf1 = *(const short8*)&Qs[l15 * 68 + 32 + g * 8];

        float m_w = -1.0e30f, l_w = 0.0f;
        f32x4 acc[4] = {};

        // ---- prologue: K fragments for iter 0 (static buffer kA) ----
        short8 kA[4], kB2[4];
        #pragma unroll
        for (int u = 0; u < 4; ++u) {
            const int f = u >> 1, ks = u & 1;
            kA[u] = *(const short8*)(
                kg + (size_t)(w * 32 + f * 16 + l15) * HEAD + ks * 32 + g * 8);
        }

        auto body = [&](int it, short8 (&kcur)[4], short8 (&knxt)[4]) {
            const int kv0 = it * 256;

            // V fragments for current iteration (consumed after softmax)
            short8 vc0, vc1, vc2, vc3;
            {
                const size_t vb = (size_t)l15 * SEQ + kv0 + w * 32 + g * 8;
                vc0 = *(const short8*)(vg + vb);
                vc1 = *(const short8*)(vg + vb + (size_t)16 * SEQ);
                vc2 = *(const short8*)(vg + vb + (size_t)32 * SEQ);
                vc3 = *(const short8*)(vg + vb + (size_t)48 * SEQ);
            }

            // K prefetch for next iteration
            if (it + 1 < iters) {
                #pragma unroll
                for (int u = 0; u < 4; ++u) {
                    const int f = u >> 1, ks = u & 1;
                    knxt[u] = *(const short8*)(
                        kg + (size_t)(kv0 + 256 + w * 32 + f * 16 + l15) * HEAD
                           + ks * 32 + g * 8);
                }
            }

            // ---- QK^T (swapped): S^T[kv 32][q 16] ----
            f32x4 sA[2] = {};
            sA[0] = __builtin_amdgcn_mfma_f32_16x16x32_bf16(kcur[0], qf0, sA[0], 0, 0, 0);
            sA[0] = __builtin_amdgcn_mfma_f32_16x16x32_bf16(kcur[1], qf1, sA[0], 0, 0, 0);
            sA[1] = __builtin_amdgcn_mfma_f32_16x16x32_bf16(kcur[2], qf0, sA[1], 0, 0, 0);
            sA[1] = __builtin_amdgcn_mfma_f32_16x16x32_bf16(kcur[3], qf1, sA[1], 0, 0, 0);

            // ---- causal mask (only last iteration crosses the diagonal) ----
            if (it == iters - 1) {
                const int kvb = kv0 + w * 32 + g * 4;
                const int qq  = q0 + l15;
                #pragma unroll
                for (int f = 0; f < 2; ++f)
                    #pragma unroll
                    for (int r = 0; r < 4; ++r)
                        if (kvb + f * 16 + r > qq) sA[f][r] = -1.0e30f;
            }

            // ---- per-wave online softmax (q = l15, copies over g) ----
            float smax = sA[0][0];
            #pragma unroll
            for (int r = 1; r < 4; ++r) smax = fmaxf(smax, sA[0][r]);
            #pragma unroll
            for (int r = 0; r < 4; ++r) smax = fmaxf(smax, sA[1][r]);
            smax = fmaxf(smax, __shfl_xor(smax, 16));
            smax = fmaxf(smax, __shfl_xor(smax, 32));

            const float mnew = fmaxf(m_w, smax);
            const float corr = __expf(m_w - mnew);
            float pv[8], psum = 0.0f;
            #pragma unroll
            for (int f = 0; f < 2; ++f)
                #pragma unroll
                for (int r = 0; r < 4; ++r) {
                    pv[f * 4 + r] = __expf(sA[f][r] - mnew);
                    psum += pv[f * 4 + r];
                }
            psum += __shfl_xor(psum, 16);
            psum += __shfl_xor(psum, 32);
            l_w = l_w * corr + psum;
            m_w = mnew;

            // ---- pack P via wave-private LDS (no barrier) ----
            #pragma unroll
            for (int f = 0; f < 2; ++f) {
                short4v pk;
                pk[0] = f2bf(pv[f*4+0]); pk[1] = f2bf(pv[f*4+1]);
                pk[2] = f2bf(pv[f*4+2]); pk[3] = f2bf(pv[f*4+3]);
                *(short4v*)&Ps[w][l15 * 40 + f * 16 + g * 4] = pk;
            }

            // ---- rescale acc ----
            float cf[4];
            #pragma unroll
            for (int r = 0; r < 4; ++r) cf[r] = __shfl(corr, g * 4 + r);
            #pragma unroll
            for (int ni = 0; ni < 4; ++ni)
                #pragma unroll
                for (int r = 0; r < 4; ++r) acc[ni][r] *= cf[r];

            // ---- PV ----
            const short8 pf = *(const short8*)&Ps[w][l15 * 40 + g * 8];
            acc[0] = __builtin_amdgcn_mfma_f32_16x16x32_bf16(pf, vc0, acc[0], 0, 0, 0);
            acc[1] = __builtin_amdgcn_mfma_f32_16x16x32_bf16(pf, vc1, acc[1], 0, 0, 0);
            acc[2] = __builtin_amdgcn_mfma_f32_16x16x32_bf16(pf, vc2, acc[2], 0, 0, 0);
            acc[3] = __builtin_amdgcn_mfma_f32_16x16x32_bf16(pf, vc3, acc[3], 0, 0, 0);
        };

        #pragma unroll 1
        for (int itp = 0; itp < iters; itp += 2) {
            body(itp, kA, kB2);
            if (itp + 1 < iters) body(itp + 1, kB2, kA);
        }

        // ---- merge 8 wave-partials (flash-decoding combine) ----
        if (lane < 16) { Sm[w * 16 + lane] = m_w; Sl[w * 16 + lane] = l_w; }
        #pragma unroll
        for (int ni = 0; ni < 4; ++ni)
            #pragma unroll
            for (int r = 0; r < 4; ++r)
                Cs[w][(g * 4 + r) * 68 + ni * 16 + l15] = acc[ni][r];
        __syncthreads();

        if (tid < 256) {
            const int q = tid >> 4, d4 = (tid & 15) * 4;
            float mg = Sm[q];
            #pragma unroll
            for (int ww = 1; ww < 8; ++ww) mg = fmaxf(mg, Sm[ww * 16 + q]);
            f32x4 o = {0.f, 0.f, 0.f, 0.f};
            float lt = 0.0f;
            #pragma unroll
            for (int ww = 0; ww < 8; ++ww) {
                const float f = __expf(Sm[ww * 16 + q] - mg);
                lt += Sl[ww * 16 + q] * f;
                f32x4 c4 = *(const f32x4*)&Cs[ww][q * 68 + d4];
                o[0] += c4[0] * f; o[1] += c4[1] * f;
                o[2] += c4[2] * f; o[3] += c4[3] * f;
            }
            const float inv = 1.0f / lt;
            f32x4 res = {o[0]*inv, o[1]*inv, o[2]*inv, o[3]*inv};
            *(f32x4*)(out + ((size_t)b * SEQ + q0 + q) * HEAD + d4) = res;
        }
        __syncthreads();
    }
}

// ---------------------------------------------------------------------------
extern "C" void kernel_launch(void* const* d_in, const int* in_sizes, int n_in,
                              void* d_out, int out_size, void* d_ws, size_t ws_size,
                              hipStream_t stream) {
    const float* x  = (const float*)d_in[0];
    const float* Wq = (const float*)d_in[1];
    const float* bq = (const float*)d_in[2];
    const float* Wk = (const float*)d_in[3];
    const float* bk = (const float*)d_in[4];
    const float* Wv = (const float*)d_in[5];
    const float* bv = (const float*)d_in[6];

    unsigned short* Wt  = (unsigned short*)d_ws;                  // 384 KB
    unsigned short* qbp = Wt + (size_t)192 * D_MODEL;             // 1 MB
    unsigned short* kbp = qbp + (size_t)ROWS * HEAD;              // 1 MB
    unsigned short* vtp = kbp + (size_t)ROWS * HEAD;              // 1 MB (V^T)
    float* o = (float*)d_out;

    conv_w  <<<dim3(48),     dim3(256), 0, stream>>>(Wq, Wk, Wv, Wt);
    gemm_qkv<<<dim3(512),    dim3(256), 0, stream>>>(x, Wt, bq, bk, bv, qbp, kbp, vtp);
    attn_fwd<<<dim3(64, 4),  dim3(512), 0, stream>>>(qbp, kbp, vtp, o);
}